// Round 1
// baseline (646.178 us; speedup 1.0000x reference)
//
#include <hip/hip_runtime.h>

#define NV   20000
#define MAXN 16
#define CC   32
#define NN   8
#define BB   8

// ---------------------------------------------------------------------------
// Mask dtype detection: jax bool masks may arrive as 1-byte bools, int32, or
// float32 depending on harness conversion. Classify deterministically.
// flag: 0 = int32 (words all 0/1), 2 = float32 (words all 0 / 0x3F800000),
//       1 = byte bool (anything else).
// ---------------------------------------------------------------------------
__global__ void detect_mask_kind(const unsigned int* __restrict__ m,
                                 int* __restrict__ flag) {
    if (threadIdx.x == 0 && blockIdx.x == 0) {
        int allint = 1, allflt = 1;
        #pragma unroll 8
        for (int k = 0; k < 64; ++k) {
            unsigned w = m[k];
            if (!(w == 0u || w == 1u)) allint = 0;
            if (!(w == 0u || w == 0x3F800000u)) allflt = 0;
        }
        *flag = allint ? 0 : (allflt ? 2 : 1);
    }
}

__device__ __forceinline__ float dot8(const float* w, const float4& a, const float4& b) {
    return fmaf(w[0], a.x, fmaf(w[1], a.y, fmaf(w[2], a.z, fmaf(w[3], a.w,
           fmaf(w[4], b.x, fmaf(w[5], b.y, fmaf(w[6], b.z, w[7] * b.w)))))));
}

// sum over the 32 lanes of each 32-lane half (reduces over c = lane&31)
__device__ __forceinline__ float xred32(float v) {
    v += __shfl_xor(v, 1);
    v += __shfl_xor(v, 2);
    v += __shfl_xor(v, 4);
    v += __shfl_xor(v, 8);
    v += __shfl_xor(v, 16);
    return v;
}

__global__ void __launch_bounds__(256)
ge_attn_kernel(const float* __restrict__ x,
               const int*   __restrict__ neighbors,
               const void*  __restrict__ maskp,
               const float* __restrict__ ptm,
               const float* __restrict__ rpu,
               const float* __restrict__ rr,
               const float* __restrict__ vb0,
               const float* __restrict__ vb1,
               const float* __restrict__ vb2,
               const float* __restrict__ qc,
               const float* __restrict__ kc,
               const float* __restrict__ w0p,
               const float* __restrict__ w1p,
               const float* __restrict__ w2p,
               const int*   __restrict__ mflag,
               float*       __restrict__ out) {
    const int t = threadIdx.x;
    const int c = t & 31;   // channel (all 32 within each wave half)
    const int i = t >> 5;   // rep index 0..7
    const int mf = *mflag;

    // ---- per-thread weight rows (computed once per block, ~512 FMA) ----
    float WQr[8], WKr[8], W0r[8], W1r0[8], W1r1[8], W2r0[8], W2r1[8], W2r2[8];
    #pragma unroll
    for (int j = 0; j < 8; ++j) {
        WQr[j] = 0.f; WKr[j] = 0.f; W0r[j] = 0.f; W1r0[j] = 0.f;
        W1r1[j] = 0.f; W2r0[j] = 0.f; W2r1[j] = 0.f; W2r2[j] = 0.f;
    }
    #pragma unroll
    for (int b = 0; b < BB; ++b) {
        const float qcb = qc[c * 8 + b];
        const float kcb = kc[c * 8 + b];
        const float w0b = w0p[c * 8 + b];
        const float w1b = w1p[c * 8 + b];
        const float w2b = w2p[c * 8 + b];
        const float* rrb = rr  + b * 64  + i * 8;
        const float* z0  = vb0 + b * 64  + i * 8;
        const float* z1  = vb1 + b * 128 + i * 8;   // [b][o][i][j], o stride 64
        const float* z2  = vb2 + b * 192 + i * 8;   // [b][o][i][j], o stride 64
        #pragma unroll
        for (int j = 0; j < 8; ++j) {
            const float r = rrb[j];
            WQr[j]  = fmaf(qcb, r, WQr[j]);
            WKr[j]  = fmaf(kcb, r, WKr[j]);
            W0r[j]  = fmaf(w0b, z0[j],       W0r[j]);
            W1r0[j] = fmaf(w1b, z1[j],       W1r0[j]);
            W1r1[j] = fmaf(w1b, z1[64 + j],  W1r1[j]);
            W2r0[j] = fmaf(w2b, z2[j],       W2r0[j]);
            W2r1[j] = fmaf(w2b, z2[64 + j],  W2r1[j]);
            W2r2[j] = fmaf(w2b, z2[128 + j], W2r2[j]);
        }
    }

    // LDS: rows padded to stride 12 floats (48 B): 16B-aligned rows,
    // conflict-free banks for the 8-row broadcast b128 reads.
    __shared__ __align__(16) float xnb[2][32 * 12];
    __shared__ __align__(16) float fl[2][32 * 12];
    __shared__ float sqv[2][8];
    __shared__ int   nbs[16];
    __shared__ int   mskl[16];
    __shared__ float usl[32];

    for (int v = blockIdx.x; v < NV; v += gridDim.x) {
        __syncthreads();  // previous vertex finished reading nbs/usl/mskl
        if (t < 16) {
            nbs[t] = neighbors[v * 16 + t];
            int mm;
            if (mf == 0)      mm = (((const int*)maskp)[(size_t)v * 16 + t] != 0);
            else if (mf == 1) mm = (((const unsigned char*)maskp)[(size_t)v * 16 + t] != 0);
            else              mm = (((const float*)maskp)[(size_t)v * 16 + t] != 0.0f);
            mskl[t] = mm;
        }
        if (t < 32) usl[t] = rpu[(size_t)v * 32 + t];

        // K[i] = sum_c sum_j WK[c,i,j] x[v,c,j] (in-wave reduce over c)
        const float* xv = x + (size_t)v * 256 + c * 8;
        const float4 xa = *(const float4*)xv;
        const float4 xb = *(const float4*)(xv + 4);
        const float kreg = xred32(dot8(WKr, xa, xb));
        __syncthreads();

        float acc = 0.f, ssum = 0.f;
        int bp = 0;
        for (int n = 0; n < MAXN; ++n) {
            if (!mskl[n]) continue;  // uniform: masked neighbor contributes 0
            const int nb = nbs[n];
            // stage neighbor feature 1KB coalesced -> LDS
            xnb[bp][(t >> 3) * 12 + (t & 7)] = x[(size_t)nb * 256 + t];
            __syncthreads();
            // f'[c,i] = sum_j P[i,j] * xn[c,j]
            const float* Pp = ptm + ((size_t)v * 16 + n) * 64 + i * 8;
            const float4 p0 = *(const float4*)Pp;
            const float4 p1 = *(const float4*)(Pp + 4);
            const float* xr = &xnb[bp][c * 12];
            const float4 x0 = *(const float4*)xr;
            const float4 x1 = *(const float4*)(xr + 4);
            float f = fmaf(p0.x, x0.x, fmaf(p0.y, x0.y, fmaf(p0.z, x0.z, fmaf(p0.w, x0.w,
                      fmaf(p1.x, x1.x, fmaf(p1.y, x1.y, fmaf(p1.z, x1.z, p1.w * x1.w)))))));
            fl[bp][c * 12 + i] = f;
            __syncthreads();
            const float* frp = &fl[bp][c * 12];
            const float4 f0 = *(const float4*)frp;
            const float4 f1 = *(const float4*)(frp + 4);
            // Q[i] and score
            float q = xred32(dot8(WQr, f0, f1));
            if ((t & 31) == 0) sqv[bp][i] = fmaxf(q + kreg, 0.f);
            __syncthreads();
            const float score = 0.125f * (sqv[bp][0] + sqv[bp][1] + sqv[bp][2] + sqv[bp][3] +
                                          sqv[bp][4] + sqv[bp][5] + sqv[bp][6] + sqv[bp][7]);
            // values: 6 register dots + u-polynomial combine
            const float u0 = usl[2 * n], u1 = usl[2 * n + 1];
            const float y0 = dot8(W0r,  f0, f1);
            const float y1 = dot8(W1r0, f0, f1);
            const float y2 = dot8(W1r1, f0, f1);
            const float y3 = dot8(W2r0, f0, f1);
            const float y4 = dot8(W2r1, f0, f1);
            const float y5 = dot8(W2r2, f0, f1);
            float val = fmaf(u0, y1, y0);
            val = fmaf(u1, y2, val);
            val = fmaf(u0 * u0, y3, val);
            val = fmaf(2.f * u0 * u1, y4, val);
            val = fmaf(u1 * u1, y5, val);
            acc  = fmaf(score, val, acc);
            ssum += score;
            bp ^= 1;
        }
        out[(size_t)v * 256 + c * 8 + i] = acc / fmaxf(ssum, 1e-8f);
    }
}

extern "C" void kernel_launch(void* const* d_in, const int* in_sizes, int n_in,
                              void* d_out, int out_size, void* d_ws, size_t ws_size,
                              hipStream_t stream) {
    const float* x         = (const float*)d_in[0];
    const int*   neighbors = (const int*)d_in[1];
    const void*  maskp     = d_in[2];
    const float* ptm       = (const float*)d_in[3];
    const float* rpu       = (const float*)d_in[4];
    const float* rr        = (const float*)d_in[5];
    const float* vb0       = (const float*)d_in[6];
    const float* vb1       = (const float*)d_in[7];
    const float* vb2       = (const float*)d_in[8];
    const float* qc        = (const float*)d_in[9];
    const float* kc        = (const float*)d_in[10];
    const float* w0p       = (const float*)d_in[11];
    const float* w1p       = (const float*)d_in[12];
    const float* w2p       = (const float*)d_in[13];
    float* out = (float*)d_out;
    int* flag = (int*)d_ws;

    detect_mask_kind<<<1, 64, 0, stream>>>((const unsigned int*)maskp, flag);
    ge_attn_kernel<<<1024, 256, 0, stream>>>(x, neighbors, maskp, ptm, rpu,
                                             rr, vb0, vb1, vb2,
                                             qc, kc, w0p, w1p, w2p,
                                             flag, out);
}

// Round 2
// 605.065 us; speedup vs baseline: 1.0679x; 1.0679x over previous
//
#include <hip/hip_runtime.h>

#define NV   20000
#define MAXN 16
#define VPB  8      // vertices per block (NV / 2500 blocks)
#define NBLK 2500

// ---------------------------------------------------------------------------
// Mask dtype detection (bool may arrive as int32 / byte / float32).
// flag: 0 = int32 words, 2 = float32 pattern, 1 = byte bool.
// ---------------------------------------------------------------------------
__global__ void detect_mask_kind(const unsigned int* __restrict__ m,
                                 int* __restrict__ flag) {
    if (threadIdx.x == 0 && blockIdx.x == 0) {
        int allint = 1, allflt = 1;
        #pragma unroll 8
        for (int k = 0; k < 64; ++k) {
            unsigned w = m[k];
            if (!(w == 0u || w == 1u)) allint = 0;
            if (!(w == 0u || w == 0x3F800000u)) allflt = 0;
        }
        *flag = allint ? 0 : (allflt ? 2 : 1);
    }
}

__device__ __forceinline__ float dot8a(const float* __restrict__ w,
                                       const float* __restrict__ f) {
    float s = w[0] * f[0];
    #pragma unroll
    for (int j = 1; j < 8; ++j) s = fmaf(w[j], f[j], s);
    return s;
}

// reduce over c: sum across the 32 lanes of each 32-lane half
__device__ __forceinline__ float xred32(float v) {
    v += __shfl_xor(v, 1);
    v += __shfl_xor(v, 2);
    v += __shfl_xor(v, 4);
    v += __shfl_xor(v, 8);
    v += __shfl_xor(v, 16);
    return v;
}

__global__ void __launch_bounds__(256, 4)
ge_attn_kernel(const float* __restrict__ x,
               const int*   __restrict__ neighbors,
               const void*  __restrict__ maskp,
               const float* __restrict__ ptm,
               const float* __restrict__ rpu,
               const float* __restrict__ rr,
               const float* __restrict__ vb0,
               const float* __restrict__ vb1,
               const float* __restrict__ vb2,
               const float* __restrict__ qc,
               const float* __restrict__ kc,
               const float* __restrict__ w0p,
               const float* __restrict__ w1p,
               const float* __restrict__ w2p,
               const int*   __restrict__ mflag,
               float*       __restrict__ out) {
    const int t = threadIdx.x;
    const int c = t & 31;   // channel
    const int i = t >> 5;   // rep index 0..7
    const int w = t >> 6;   // wave id 0..3
    const int mf = *mflag;

    // ---- per-thread combined weight rows (once per block, ~512 FMA) ----
    float WQr[8], WKr[8], W0r[8], W1r0[8], W1r1[8], W2r0[8], W2r1[8], W2r2[8];
    #pragma unroll
    for (int j = 0; j < 8; ++j) {
        WQr[j] = 0.f; WKr[j] = 0.f; W0r[j] = 0.f; W1r0[j] = 0.f;
        W1r1[j] = 0.f; W2r0[j] = 0.f; W2r1[j] = 0.f; W2r2[j] = 0.f;
    }
    #pragma unroll
    for (int b = 0; b < 8; ++b) {
        const float qcb = qc[c * 8 + b];
        const float kcb = kc[c * 8 + b];
        const float w0b = w0p[c * 8 + b];
        const float w1b = w1p[c * 8 + b];
        const float w2b = w2p[c * 8 + b];
        const float* rrb = rr  + b * 64  + i * 8;
        const float* z0  = vb0 + b * 64  + i * 8;
        const float* z1  = vb1 + b * 128 + i * 8;   // [b][o][i][j]
        const float* z2  = vb2 + b * 192 + i * 8;
        #pragma unroll
        for (int j = 0; j < 8; ++j) {
            const float r = rrb[j];
            WQr[j]  = fmaf(qcb, r, WQr[j]);
            WKr[j]  = fmaf(kcb, r, WKr[j]);
            W0r[j]  = fmaf(w0b, z0[j],       W0r[j]);
            W1r0[j] = fmaf(w1b, z1[j],       W1r0[j]);
            W1r1[j] = fmaf(w1b, z1[64 + j],  W1r1[j]);
            W2r0[j] = fmaf(w2b, z2[j],       W2r0[j]);
            W2r1[j] = fmaf(w2b, z2[64 + j],  W2r1[j]);
            W2r2[j] = fmaf(w2b, z2[128 + j], W2r2[j]);
        }
    }

    // only cross-wave datum: per-wave score partials, double-buffered
    __shared__ __align__(16) float swv[2][16][4];

    const int vbase = blockIdx.x * VPB;
    for (int vi = 0; vi < VPB; ++vi) {
        const int v  = vbase + vi;
        const int bp = vi & 1;
        const int vq = v * 16;

        // uniform loads: neighbor ids + mask (SALU/broadcast)
        int nb[16];
        unsigned livemask = 0;
        #pragma unroll
        for (int n = 0; n < 16; ++n) {
            nb[n] = neighbors[vq + n];
            int mm;
            if (mf == 0)      mm = (((const int*)maskp)[vq + n] != 0);
            else if (mf == 1) mm = (((const unsigned char*)maskp)[vq + n] != 0);
            else              mm = (((const float*)maskp)[vq + n] != 0.0f);
            if (mm) livemask |= (1u << n);
        }

        // K[i] (this thread's i), reduced over c in-wave
        float xc[8];
        {
            const float* xv = x + (size_t)v * 256 + c * 8;
            *(float4*)&xc[0] = *(const float4*)xv;
            *(float4*)&xc[4] = *(const float4*)(xv + 4);
        }
        const float kreg = xred32(dot8a(WKr, xc));

        float vals[16];
        float acc = 0.f, ssum = 0.f;

        #pragma unroll
        for (int n = 0; n < 16; ++n) {
            if (!(livemask & (1u << n))) continue;
            // neighbor feature row (global, 32B lane stride, L2-resident)
            float xn[8];
            {
                const float* xnp = x + (size_t)nb[n] * 256 + c * 8;
                *(float4*)&xn[0] = *(const float4*)xnp;
                *(float4*)&xn[4] = *(const float4*)(xnp + 4);
            }
            // full transported row f'[c,0:8] (P is block-uniform -> scalar loads)
            const float* Pp = ptm + (size_t)(vq + n) * 64;
            float f[8];
            #pragma unroll
            for (int j = 0; j < 8; ++j) {
                float p[8];
                *(float4*)&p[0] = *(const float4*)(Pp + j * 8);
                *(float4*)&p[4] = *(const float4*)(Pp + j * 8 + 4);
                f[j] = dot8a(p, xn);
            }
            // score partial: Q[i] reduced over c, relu, i-pair sum in-wave
            const float q = xred32(dot8a(WQr, f));
            const float r = fmaxf(q + kreg, 0.f);
            const float s = r + __shfl_xor(r, 32);
            if ((t & 63) == 0) swv[bp][n][w] = s;
            // value scalar for this (c,i): 6 dots + u-polynomial
            const float u0 = rpu[(size_t)(vq + n) * 2];
            const float u1 = rpu[(size_t)(vq + n) * 2 + 1];
            const float y0 = dot8a(W0r,  f);
            const float y1 = dot8a(W1r0, f);
            const float y2 = dot8a(W1r1, f);
            const float y3 = dot8a(W2r0, f);
            const float y4 = dot8a(W2r1, f);
            const float y5 = dot8a(W2r2, f);
            float val = fmaf(u0, y1, y0);
            val = fmaf(u1, y2, val);
            val = fmaf(u0 * u0, y3, val);
            val = fmaf(2.f * u0 * u1, y4, val);
            val = fmaf(u1 * u1, y5, val);
            vals[n] = val;
        }

        __syncthreads();   // publish swv[bp]; one barrier per vertex

        #pragma unroll
        for (int n = 0; n < 16; ++n) {
            if (!(livemask & (1u << n))) continue;
            const float4 sv = *(const float4*)&swv[bp][n][0];
            const float sc = 0.125f * (sv.x + sv.y + sv.z + sv.w);
            ssum += sc;
            acc  = fmaf(sc, vals[n], acc);
        }
        out[(size_t)v * 256 + c * 8 + i] = acc / fmaxf(ssum, 1e-8f);
    }
}

extern "C" void kernel_launch(void* const* d_in, const int* in_sizes, int n_in,
                              void* d_out, int out_size, void* d_ws, size_t ws_size,
                              hipStream_t stream) {
    const float* x         = (const float*)d_in[0];
    const int*   neighbors = (const int*)d_in[1];
    const void*  maskp     = d_in[2];
    const float* ptm       = (const float*)d_in[3];
    const float* rpu       = (const float*)d_in[4];
    const float* rr        = (const float*)d_in[5];
    const float* vb0       = (const float*)d_in[6];
    const float* vb1       = (const float*)d_in[7];
    const float* vb2       = (const float*)d_in[8];
    const float* qc        = (const float*)d_in[9];
    const float* kc        = (const float*)d_in[10];
    const float* w0p       = (const float*)d_in[11];
    const float* w1p       = (const float*)d_in[12];
    const float* w2p       = (const float*)d_in[13];
    float* out = (float*)d_out;
    int* flag = (int*)d_ws;

    detect_mask_kind<<<1, 64, 0, stream>>>((const unsigned int*)maskp, flag);
    ge_attn_kernel<<<NBLK, 256, 0, stream>>>(x, neighbors, maskp, ptm, rpu,
                                             rr, vb0, vb1, vb2,
                                             qc, kc, w0p, w1p, w2p,
                                             flag, out);
}

// Round 3
// 472.554 us; speedup vs baseline: 1.3674x; 1.2804x over previous
//
#include <hip/hip_runtime.h>

#define NV   20000
#define MAXN 16
#define VPB  8      // vertices per block (NV / 2500 blocks)
#define NBLK 2500

// ---------------------------------------------------------------------------
// Mask dtype detection (bool may arrive as int32 / byte / float32).
// flag: 0 = int32 words, 2 = float32 pattern, 1 = byte bool.
// ---------------------------------------------------------------------------
__global__ void detect_mask_kind(const unsigned int* __restrict__ m,
                                 int* __restrict__ flag) {
    if (threadIdx.x == 0 && blockIdx.x == 0) {
        int allint = 1, allflt = 1;
        #pragma unroll 8
        for (int k = 0; k < 64; ++k) {
            unsigned w = m[k];
            if (!(w == 0u || w == 1u)) allint = 0;
            if (!(w == 0u || w == 0x3F800000u)) allflt = 0;
        }
        *flag = allint ? 0 : (allflt ? 2 : 1);
    }
}

__device__ __forceinline__ float dot8a(const float* __restrict__ w,
                                       const float* __restrict__ f) {
    float s = w[0] * f[0];
    #pragma unroll
    for (int j = 1; j < 8; ++j) s = fmaf(w[j], f[j], s);
    return s;
}

// reduce over c: sum across the 32 lanes of each 32-lane half
__device__ __forceinline__ float xred32(float v) {
    v += __shfl_xor(v, 1);
    v += __shfl_xor(v, 2);
    v += __shfl_xor(v, 4);
    v += __shfl_xor(v, 8);
    v += __shfl_xor(v, 16);
    return v;
}

// min 3 waves/EU -> VGPR cap ~170: room for the 64-float weight set with
// ZERO spills (R2's launch_bounds(256,4) made the allocator pick 64 VGPRs
// and spill the weight rows to scratch: WRITE_SIZE 57.5MB vs 20.5MB output).
__global__ void __launch_bounds__(256, 3)
ge_attn_kernel(const float* __restrict__ x,
               const int*   __restrict__ neighbors,
               const void*  __restrict__ maskp,
               const float* __restrict__ ptm,
               const float* __restrict__ rpu,
               const float* __restrict__ rr,
               const float* __restrict__ vb0,
               const float* __restrict__ vb1,
               const float* __restrict__ vb2,
               const float* __restrict__ qc,
               const float* __restrict__ kc,
               const float* __restrict__ w0p,
               const float* __restrict__ w1p,
               const float* __restrict__ w2p,
               const int*   __restrict__ mflag,
               float*       __restrict__ out) {
    const int t = threadIdx.x;
    const int c = t & 31;   // channel
    const int i = t >> 5;   // rep index 0..7
    const int w = t >> 6;   // wave id 0..3
    const int mf = *mflag;

    // ---- per-thread combined weight rows (once per block, ~512 FMA) ----
    float WQr[8], WKr[8], W0r[8], W1r0[8], W1r1[8], W2r0[8], W2r1[8], W2r2[8];
    #pragma unroll
    for (int j = 0; j < 8; ++j) {
        WQr[j] = 0.f; WKr[j] = 0.f; W0r[j] = 0.f; W1r0[j] = 0.f;
        W1r1[j] = 0.f; W2r0[j] = 0.f; W2r1[j] = 0.f; W2r2[j] = 0.f;
    }
    #pragma unroll
    for (int b = 0; b < 8; ++b) {
        const float qcb = qc[c * 8 + b];
        const float kcb = kc[c * 8 + b];
        const float w0b = w0p[c * 8 + b];
        const float w1b = w1p[c * 8 + b];
        const float w2b = w2p[c * 8 + b];
        const float* rrb = rr  + b * 64  + i * 8;
        const float* z0  = vb0 + b * 64  + i * 8;
        const float* z1  = vb1 + b * 128 + i * 8;   // [b][o][i][j]
        const float* z2  = vb2 + b * 192 + i * 8;
        #pragma unroll
        for (int j = 0; j < 8; ++j) {
            const float r = rrb[j];
            WQr[j]  = fmaf(qcb, r, WQr[j]);
            WKr[j]  = fmaf(kcb, r, WKr[j]);
            W0r[j]  = fmaf(w0b, z0[j],       W0r[j]);
            W1r0[j] = fmaf(w1b, z1[j],       W1r0[j]);
            W1r1[j] = fmaf(w1b, z1[64 + j],  W1r1[j]);
            W2r0[j] = fmaf(w2b, z2[j],       W2r0[j]);
            W2r1[j] = fmaf(w2b, z2[64 + j],  W2r1[j]);
            W2r2[j] = fmaf(w2b, z2[128 + j], W2r2[j]);
        }
    }

    // only cross-wave datum: per-wave score partials, double-buffered
    __shared__ __align__(16) float swv[2][16][4];

    const int vbase = blockIdx.x * VPB;
    for (int vi = 0; vi < VPB; ++vi) {
        const int v  = vbase + vi;
        const int bp = vi & 1;
        const int vq = v * 16;

        // uniform loads: neighbor ids + mask (SALU/broadcast)
        int nb[16];
        unsigned livemask = 0;
        #pragma unroll
        for (int n = 0; n < 16; ++n) {
            nb[n] = neighbors[vq + n];
            int mm;
            if (mf == 0)      mm = (((const int*)maskp)[vq + n] != 0);
            else if (mf == 1) mm = (((const unsigned char*)maskp)[vq + n] != 0);
            else              mm = (((const float*)maskp)[vq + n] != 0.0f);
            if (mm) livemask |= (1u << n);
        }

        // K[i] (this thread's i), reduced over c in-wave
        float xc[8];
        {
            const float* xv = x + (size_t)v * 256 + c * 8;
            *(float4*)&xc[0] = *(const float4*)xv;
            *(float4*)&xc[4] = *(const float4*)(xv + 4);
        }
        const float kreg = xred32(dot8a(WKr, xc));

        float vals[16];
        float acc = 0.f, ssum = 0.f;

        #pragma unroll
        for (int n = 0; n < 16; ++n) {
            if (!(livemask & (1u << n))) continue;
            // neighbor feature row (global, 32B lane stride, L2/L3-resident)
            float xn[8];
            {
                const float* xnp = x + (size_t)nb[n] * 256 + c * 8;
                *(float4*)&xn[0] = *(const float4*)xnp;
                *(float4*)&xn[4] = *(const float4*)(xnp + 4);
            }
            // full transported row f'[c,0:8] (P is block-uniform -> scalar loads)
            const float* Pp = ptm + (size_t)(vq + n) * 64;
            float f[8];
            #pragma unroll
            for (int j = 0; j < 8; ++j) {
                float p[8];
                *(float4*)&p[0] = *(const float4*)(Pp + j * 8);
                *(float4*)&p[4] = *(const float4*)(Pp + j * 8 + 4);
                f[j] = dot8a(p, xn);
            }
            // score partial: Q[i] reduced over c, relu, i-pair sum in-wave
            const float q = xred32(dot8a(WQr, f));
            const float r = fmaxf(q + kreg, 0.f);
            const float s = r + __shfl_xor(r, 32);
            if ((t & 63) == 0) swv[bp][n][w] = s;
            // value scalar for this (c,i): 6 dots + u-polynomial
            const float u0 = rpu[(size_t)(vq + n) * 2];
            const float u1 = rpu[(size_t)(vq + n) * 2 + 1];
            const float y0 = dot8a(W0r,  f);
            const float y1 = dot8a(W1r0, f);
            const float y2 = dot8a(W1r1, f);
            const float y3 = dot8a(W2r0, f);
            const float y4 = dot8a(W2r1, f);
            const float y5 = dot8a(W2r2, f);
            float val = fmaf(u0, y1, y0);
            val = fmaf(u1, y2, val);
            val = fmaf(u0 * u0, y3, val);
            val = fmaf(2.f * u0 * u1, y4, val);
            val = fmaf(u1 * u1, y5, val);
            vals[n] = val;
        }

        __syncthreads();   // publish swv[bp]; one barrier per vertex

        #pragma unroll
        for (int n = 0; n < 16; ++n) {
            if (!(livemask & (1u << n))) continue;
            const float4 sv = *(const float4*)&swv[bp][n][0];
            const float sc = 0.125f * (sv.x + sv.y + sv.z + sv.w);
            ssum += sc;
            acc  = fmaf(sc, vals[n], acc);
        }
        out[(size_t)v * 256 + c * 8 + i] = acc / fmaxf(ssum, 1e-8f);
    }
}

extern "C" void kernel_launch(void* const* d_in, const int* in_sizes, int n_in,
                              void* d_out, int out_size, void* d_ws, size_t ws_size,
                              hipStream_t stream) {
    const float* x         = (const float*)d_in[0];
    const int*   neighbors = (const int*)d_in[1];
    const void*  maskp     = d_in[2];
    const float* ptm       = (const float*)d_in[3];
    const float* rpu       = (const float*)d_in[4];
    const float* rr        = (const float*)d_in[5];
    const float* vb0       = (const float*)d_in[6];
    const float* vb1       = (const float*)d_in[7];
    const float* vb2       = (const float*)d_in[8];
    const float* qc        = (const float*)d_in[9];
    const float* kc        = (const float*)d_in[10];
    const float* w0p       = (const float*)d_in[11];
    const float* w1p       = (const float*)d_in[12];
    const float* w2p       = (const float*)d_in[13];
    float* out = (float*)d_out;
    int* flag = (int*)d_ws;

    detect_mask_kind<<<1, 64, 0, stream>>>((const unsigned int*)maskp, flag);
    ge_attn_kernel<<<NBLK, 256, 0, stream>>>(x, neighbors, maskp, ptm, rpu,
                                             rr, vb0, vb1, vb2,
                                             qc, kc, w0p, w1p, w2p,
                                             flag, out);
}